// Round 4
// baseline (147.561 us; speedup 1.0000x reference)
//
#include <hip/hip_runtime.h>

#define NN 2048
#define DIMM 256
#define HEADS 8
#define HEAD_DIM 32
#define EXPH 16
#define E_EDGES 32768
#define VDIM 512          // EXPH*HEAD_DIM
#define PW 1024           // P row width: [q 256 | k*scale 256 | vv 512]
#define SCALE_F 0.17677669529663687f
#define MASKV -1.0e9f
#define MAXD 128
#define CS_BLOCKS 128
#define CS_ROWS (NN / CS_BLOCKS)   // 16

// ---------- edge-index dtype detection + deg/cursor zero (replaces 2 memsets) ----------
__global__ void detect_init_kernel(const int* __restrict__ ei32, int* __restrict__ flag,
                                   int* __restrict__ deg, int* __restrict__ cursor) {
    int b = blockIdx.x;
    int t = threadIdx.x;
    if (b == 0) {
        __shared__ int nz;
        if (t == 0) nz = 0;
        __syncthreads();
        if (ei32[2 * t + 1] != 0) atomicAdd(&nz, 1);
        __syncthreads();
        if (t == 0) flag[0] = (nz == 0) ? 1 : 0;  // 1 => int64
    } else {
        int idx = (b - 1) * 256 + t;  // blocks 1..8 cover 2048
        deg[idx] = 0;
        cursor[idx] = 0;
    }
}

__device__ __forceinline__ int load_edge(const int* __restrict__ ei32, int is64, int idx) {
    return is64 ? ei32[2 * idx] : ei32[idx];  // little-endian low word holds value (< 2^31)
}

// ---------- projections: P[n][0:256]=x@Wq^T ; [256:512]=x@Wk^T*SCALE ; [512:1024]=x@Wv^T+edges@Wev^T
// tile: 64 rows x 128 cols, 256 threads, per-thread 4x8
__global__ __launch_bounds__(256) void proj_kernel(
    const float* __restrict__ x, const float* __restrict__ edges,
    const float* __restrict__ Wq, const float* __restrict__ Wk,
    const float* __restrict__ Wv, const float* __restrict__ Wev,
    float* __restrict__ P)
{
    __shared__ float As[16][68];    // +4 pad: conflict-free
    __shared__ float Bs[16][132];
    int t = threadIdx.x;
    int rowT = blockIdx.x * 64;
    int jb = blockIdx.y;            // 0..7, 128-col tiles
    int colT = jb * 128;

    const float* W; int wbase; int nseg = 1;
    if (jb < 2)      { W = Wq; wbase = jb * 128; }
    else if (jb < 4) { W = Wk; wbase = (jb - 2) * 128; }
    else             { W = Wv; wbase = (jb - 4) * 128; nseg = 2; }

    int tm = t & 15, tn = t >> 4;   // rows tm*4.., cols tn*8..
    float acc[4][8];
    #pragma unroll
    for (int i = 0; i < 4; i++)
        #pragma unroll
        for (int j = 0; j < 8; j++) acc[i][j] = 0.f;

    int lr = t >> 2;
    int lk = (t & 3) * 4;

    for (int seg = 0; seg < nseg; ++seg) {
        const float* A  = (seg == 0) ? x : edges;
        const float* Wm = (seg == 0) ? W : Wev;
        for (int k0 = 0; k0 < DIMM; k0 += 16) {
            // A: 64x16
            {
                float4 av = *(const float4*)(A + (size_t)(rowT + lr) * DIMM + k0 + lk);
                As[lk + 0][lr] = av.x; As[lk + 1][lr] = av.y;
                As[lk + 2][lr] = av.z; As[lk + 3][lr] = av.w;
            }
            // B: 128x16 (two 64-row halves)
            #pragma unroll
            for (int it = 0; it < 2; it++) {
                int r = it * 64 + lr;
                float4 bv = *(const float4*)(Wm + (size_t)(wbase + r) * DIMM + k0 + lk);
                Bs[lk + 0][r] = bv.x; Bs[lk + 1][r] = bv.y;
                Bs[lk + 2][r] = bv.z; Bs[lk + 3][r] = bv.w;
            }
            __syncthreads();
            #pragma unroll
            for (int kk = 0; kk < 16; kk++) {
                float4 a4 = *(const float4*)&As[kk][tm * 4];
                float4 b0 = *(const float4*)&Bs[kk][tn * 8];
                float4 b1 = *(const float4*)&Bs[kk][tn * 8 + 4];
                float am[4] = {a4.x, a4.y, a4.z, a4.w};
                float bm[8] = {b0.x, b0.y, b0.z, b0.w, b1.x, b1.y, b1.z, b1.w};
                #pragma unroll
                for (int i = 0; i < 4; i++)
                    #pragma unroll
                    for (int j = 0; j < 8; j++) acc[i][j] += am[i] * bm[j];
            }
            __syncthreads();
        }
    }
    float sc = (jb == 2 || jb == 3) ? SCALE_F : 1.0f;
    #pragma unroll
    for (int i = 0; i < 4; i++) {
        int r = rowT + tm * 4 + i;
        float4 o0 = make_float4(acc[i][0] * sc, acc[i][1] * sc, acc[i][2] * sc, acc[i][3] * sc);
        float4 o1 = make_float4(acc[i][4] * sc, acc[i][5] * sc, acc[i][6] * sc, acc[i][7] * sc);
        *(float4*)&P[(size_t)r * PW + colT + tn * 8]     = o0;
        *(float4*)&P[(size_t)r * PW + colT + tn * 8 + 4] = o1;
    }
}

// ---------- colsum stage 1: partial[b][c] = sum over 16 rows of vv[.][c] ----------
__global__ __launch_bounds__(256) void colsum1_kernel(const float* __restrict__ P, float* __restrict__ partial) {
    int b = blockIdx.x;
    int t = threadIdx.x;
    int r0 = b * CS_ROWS;
    #pragma unroll
    for (int cg = 0; cg < 2; cg++) {
        int c = cg * 256 + t;
        float s = 0.f;
        #pragma unroll
        for (int r = 0; r < CS_ROWS; r++)
            s += P[(size_t)(r0 + r) * PW + 512 + c];
        partial[(size_t)b * VDIM + c] = s;
    }
}

// ---------- colsum stage 2: colsum[c] = sum_b partial[b][c] ----------
__global__ __launch_bounds__(512) void colsum2_kernel(const float* __restrict__ partial, float* __restrict__ colsum) {
    int c = threadIdx.x;  // 0..511
    float s = 0.f;
    for (int b = 0; b < CS_BLOCKS; b++) s += partial[(size_t)b * VDIM + c];
    colsum[c] = s;
}

// ---------- CSR build ----------
__global__ void hist_kernel(const int* __restrict__ ei32, const int* __restrict__ flag, int* __restrict__ deg) {
    int p = blockIdx.x * 256 + threadIdx.x;
    int is64 = flag[0];
    if (p < E_EDGES) atomicAdd(&deg[load_edge(ei32, is64, p)], 1);
}

__global__ __launch_bounds__(256) void scan_kernel(const int* __restrict__ deg, int* __restrict__ offs) {
    __shared__ int part[256];
    __shared__ int pref[257];
    int t = threadIdx.x;
    int base = t * 8;
    int s = 0;
    for (int i = 0; i < 8; i++) s += deg[base + i];
    part[t] = s;
    __syncthreads();
    if (t == 0) {
        int r = 0;
        for (int i = 0; i < 256; i++) { pref[i] = r; r += part[i]; }
        pref[256] = r;
    }
    __syncthreads();
    int run = pref[t];
    for (int i = 0; i < 8; i++) { offs[base + i] = run; run += deg[base + i]; }
    if (t == 0) offs[NN] = pref[256];
}

__global__ void fill_kernel(const int* __restrict__ ei32, const int* __restrict__ flag,
                            const int* __restrict__ offs, int* __restrict__ cursor,
                            int* __restrict__ edst, int* __restrict__ eid) {
    int p = blockIdx.x * 256 + threadIdx.x;
    int is64 = flag[0];
    if (p < E_EDGES) {
        int s = load_edge(ei32, is64, p);
        int pos = offs[s] + atomicAdd(&cursor[s], 1);
        edst[pos] = load_edge(ei32, is64, E_EDGES + p);
        eid[pos]  = p;
    }
}

// ---------- main: fused edge-dot + head-expand + softmax + Laplacian apply ----------
__global__ __launch_bounds__(256) void laplacian_kernel(
    const int* __restrict__ offs, const int* __restrict__ edst, const int* __restrict__ eid,
    const float* __restrict__ Wexp, const float* __restrict__ colsum,
    const float* __restrict__ P, float* __restrict__ out2)
{
    __shared__ int dstS[MAXD], idS[MAXD];
    __shared__ int dst2[MAXD], liveS[MAXD];
    __shared__ float ewS[MAXD][HEADS];
    __shared__ float aS[MAXD][EXPH];          // a -> exp -> normalized w (in place)
    __shared__ float WexpS[EXPH * HEADS];
    __shared__ float MeS[EXPH], rmaxS[EXPH], denomS[EXPH], wmaskS[EXPH];
    __shared__ int Dcnt;
    int n = blockIdx.x;
    int t = threadIdx.x;
    int o0 = offs[n], o1 = offs[n + 1];
    int dg = o1 - o0;
    if (dg > MAXD) dg = MAXD;  // Poisson(16): P(deg>128) ~ 0
    if (t == 0) Dcnt = 0;
    if (t < EXPH * HEADS) WexpS[t] = Wexp[t];
    if (t < dg) { dstS[t] = edst[o0 + t]; idS[t] = eid[o0 + t]; }
    __syncthreads();
    // parallel rank sort by edge id (ids unique -> rank is a permutation)
    if (t < dg) {
        int id = idS[t], d = dstS[t];
        int rank = 0;
        for (int j = 0; j < dg; j++) rank += (idS[j] < id) ? 1 : 0;
        dst2[rank] = d;
    }
    if (t < EXPH) {
        float s = 0.f;
        #pragma unroll
        for (int h = 0; h < HEADS; h++) s += MASKV * WexpS[t * HEADS + h];
        MeS[t] = s;
    }
    __syncthreads();
    // dedup: last write (max id = max rank) wins => live iff no later duplicate dst
    if (t < dg) {
        int d = dst2[t], live = 1;
        for (int j = t + 1; j < dg; j++)
            if (dst2[j] == d) { live = 0; break; }
        liveS[t] = live;
        if (live) atomicAdd(&Dcnt, 1);
    }
    // fused per-edge q.k dots (src == n for all edges of this block)
    {
        int h = t & 7;
        const float4* qr = (const float4*)(P + (size_t)n * PW + h * 32);
        for (int i = t >> 3; i < dg; i += 32) {
            const float4* kr = (const float4*)(P + (size_t)dst2[i] * PW + 256 + h * 32);
            float s = 0.f;
            #pragma unroll
            for (int m = 0; m < 8; m++) {
                float4 a = qr[m], b = kr[m];
                s += a.x * b.x + a.y * b.y + a.z * b.z + a.w * b.w;
            }
            ewS[i][h] = s;
        }
    }
    __syncthreads();
    // head-expand: a[i][e] = sum_h ew[i][h] * Wexp[e][h]
    for (int idx = t; idx < dg * EXPH; idx += 256) {
        int i = idx >> 4, e = idx & 15;
        float a = 0.f;
        #pragma unroll
        for (int hh = 0; hh < HEADS; hh++) a += ewS[i][hh] * WexpS[e * HEADS + hh];
        aS[i][e] = a;
    }
    __syncthreads();
    // row max per e
    if (t < EXPH) {
        int e = t;
        float rmax = MeS[e];
        for (int i = 0; i < dg; i++) if (liveS[i]) rmax = fmaxf(rmax, aS[i][e]);
        rmaxS[e] = rmax;
    }
    __syncthreads();
    // exps in parallel, in place
    for (int idx = t; idx < dg * EXPH; idx += 256) {
        int i = idx >> 4, e = idx & 15;
        aS[i][e] = liveS[i] ? expf(aS[i][e] - rmaxS[e]) : 0.f;
    }
    __syncthreads();
    int D = Dcnt;
    // denominator per e, deterministic sorted order
    if (t < EXPH) {
        int e = t;
        float wmE = expf(MeS[e] - rmaxS[e]);
        float denom = (float)(NN - D) * wmE;
        for (int i = 0; i < dg; i++) denom += aS[i][e];
        denomS[e] = denom;
        wmaskS[e] = wmE / denom;
    }
    __syncthreads();
    // normalize in parallel
    for (int idx = t; idx < dg * EXPH; idx += 256) {
        int i = idx >> 4, e = idx & 15;
        aS[i][e] = aS[i][e] / denomS[e];
    }
    __syncthreads();
    // out2[n][c] = vv[n][c] - wmask*colsum[c] + sum_live (wmask - w_i) * vv[dst_i][c]
    int e = t >> 4;
    float wm = wmaskS[e];
    const float2* vvn = (const float2*)(P + (size_t)n * PW + 512);
    const float2* cs2 = (const float2*)colsum;
    float2 v0 = vvn[t];
    float2 cv = cs2[t];
    float ax = v0.x - wm * cv.x;
    float ay = v0.y - wm * cv.y;
    for (int i = 0; i < dg; i++) {
        if (!liveS[i]) continue;
        float w = wm - aS[i][e];
        const float2* vr = (const float2*)(P + (size_t)dst2[i] * PW + 512);
        float2 vb = vr[t];
        ax += w * vb.x; ay += w * vb.y;
    }
    float2* o = (float2*)(out2 + (size_t)n * VDIM);
    o[t] = make_float2(ax, ay);
}

// ---------- final GEMM: C (2048x256) = out2 (2048x512) @ Wout^T (Wout 256x512) ----------
__global__ __launch_bounds__(256) void outgemm_kernel(
    const float* __restrict__ A, const float* __restrict__ W, float* __restrict__ C)
{
    __shared__ float As[16][68];
    __shared__ float Bs[16][68];
    int t = threadIdx.x;
    int rowT = blockIdx.x * 64;
    int colT = blockIdx.y * 64;
    int tm = t & 15, tn = t >> 4;
    float acc[4][4];
    #pragma unroll
    for (int i = 0; i < 4; i++)
        #pragma unroll
        for (int j = 0; j < 4; j++) acc[i][j] = 0.f;
    int lr = t >> 2;
    int lk = (t & 3) * 4;
    for (int k0 = 0; k0 < VDIM; k0 += 16) {
        float4 av = *(const float4*)(A + (size_t)(rowT + lr) * VDIM + k0 + lk);
        As[lk + 0][lr] = av.x; As[lk + 1][lr] = av.y;
        As[lk + 2][lr] = av.z; As[lk + 3][lr] = av.w;
        float4 bv = *(const float4*)(W + (size_t)(colT + lr) * VDIM + k0 + lk);
        Bs[lk + 0][lr] = bv.x; Bs[lk + 1][lr] = bv.y;
        Bs[lk + 2][lr] = bv.z; Bs[lk + 3][lr] = bv.w;
        __syncthreads();
        #pragma unroll
        for (int kk = 0; kk < 16; kk++) {
            float4 a4 = *(const float4*)&As[kk][tm * 4];
            float4 b4 = *(const float4*)&Bs[kk][tn * 4];
            float am[4] = {a4.x, a4.y, a4.z, a4.w};
            float bm[4] = {b4.x, b4.y, b4.z, b4.w};
            #pragma unroll
            for (int i = 0; i < 4; i++)
                #pragma unroll
                for (int j = 0; j < 4; j++) acc[i][j] += am[i] * bm[j];
        }
        __syncthreads();
    }
    #pragma unroll
    for (int i = 0; i < 4; i++) {
        int r = rowT + tm * 4 + i;
        *(float4*)&C[(size_t)r * DIMM + colT + tn * 4] =
            make_float4(acc[i][0], acc[i][1], acc[i][2], acc[i][3]);
    }
}

extern "C" void kernel_launch(void* const* d_in, const int* in_sizes, int n_in,
                              void* d_out, int out_size, void* d_ws, size_t ws_size,
                              hipStream_t stream) {
    const float* x     = (const float*)d_in[0];
    const float* edges = (const float*)d_in[1];
    const int*   ei32  = (const int*)d_in[2];
    const float* Wq    = (const float*)d_in[3];
    const float* Wk    = (const float*)d_in[4];
    const float* Wv    = (const float*)d_in[5];
    const float* Wev   = (const float*)d_in[6];
    const float* Wexp  = (const float*)d_in[7];
    const float* Wout  = (const float*)d_in[8];
    float* out = (float*)d_out;

    char* ws = (char*)d_ws;
    size_t off = 0;
    auto alloc = [&](size_t bytes) -> void* {
        void* p = ws + off;
        off = (off + bytes + 255) & ~(size_t)255;
        return p;
    };
    float* P       = (float*)alloc((size_t)NN * PW * 4);          // 8 MB
    float* out2    = (float*)alloc((size_t)NN * VDIM * 4);        // 4 MB
    float* partial = (float*)alloc((size_t)CS_BLOCKS * VDIM * 4); // 256 KB
    float* colsum  = (float*)alloc(VDIM * 4);
    int* flag      = (int*)alloc(4);
    int* deg       = (int*)alloc(NN * 4);
    int* cursor    = (int*)alloc(NN * 4);
    int* offs      = (int*)alloc((NN + 1) * 4);
    int* edst      = (int*)alloc(E_EDGES * 4);
    int* eid       = (int*)alloc(E_EDGES * 4);
    (void)ws_size; (void)in_sizes; (void)n_in; (void)out_size;

    detect_init_kernel<<<9, 256, 0, stream>>>(ei32, flag, deg, cursor);
    proj_kernel<<<dim3(32, 8), 256, 0, stream>>>(x, edges, Wq, Wk, Wv, Wev, P);
    colsum1_kernel<<<CS_BLOCKS, 256, 0, stream>>>(P, partial);
    colsum2_kernel<<<1, 512, 0, stream>>>(partial, colsum);
    hist_kernel<<<E_EDGES / 256, 256, 0, stream>>>(ei32, flag, deg);
    scan_kernel<<<1, 256, 0, stream>>>(deg, offs);
    fill_kernel<<<E_EDGES / 256, 256, 0, stream>>>(ei32, flag, offs, cursor, edst, eid);
    laplacian_kernel<<<NN, 256, 0, stream>>>(offs, edst, eid, Wexp, colsum, P, out2);
    outgemm_kernel<<<dim3(32, 4), 256, 0, stream>>>(out2, Wout, out);
}

// Round 5
// 126.740 us; speedup vs baseline: 1.1643x; 1.1643x over previous
//
#include <hip/hip_runtime.h>

#define NN 2048
#define DIMM 256
#define HEADS 8
#define HEAD_DIM 32
#define EXPH 16
#define E_EDGES 32768
#define VDIM 512          // EXPH*HEAD_DIM
#define PW 1024           // P row width: [q 256 | k*scale 256 | vv 512]
#define SCALE_F 0.17677669529663687f
#define MASKV -1.0e9f
#define MAXD 128
#define CS_BLOCKS 128
#define CS_ROWS (NN / CS_BLOCKS)   // 16

// ---------- edge-index dtype detection + deg/cursor zero (replaces 2 memsets) ----------
__global__ void detect_init_kernel(const int* __restrict__ ei32, int* __restrict__ flag,
                                   int* __restrict__ deg, int* __restrict__ cursor) {
    int b = blockIdx.x;
    int t = threadIdx.x;
    if (b == 0) {
        __shared__ int nz;
        if (t == 0) nz = 0;
        __syncthreads();
        if (ei32[2 * t + 1] != 0) atomicAdd(&nz, 1);
        __syncthreads();
        if (t == 0) flag[0] = (nz == 0) ? 1 : 0;  // 1 => int64
    } else {
        int idx = (b - 1) * 256 + t;  // blocks 1..8 cover 2048
        deg[idx] = 0;
        cursor[idx] = 0;
    }
}

__device__ __forceinline__ int load_edge(const int* __restrict__ ei32, int is64, int idx) {
    return is64 ? ei32[2 * idx] : ei32[idx];  // little-endian low word holds value (< 2^31)
}

// ---------- projections: P[n][0:256]=x@Wq^T ; [256:512]=x@Wk^T*SCALE ; [512:1024]=x@Wv^T+edges@Wev^T
// tile: 32 rows x 64 cols, 256 threads, per-thread 2x4; grid (64,16) = 1024 blocks (4/CU)
__global__ __launch_bounds__(256) void proj_kernel(
    const float* __restrict__ x, const float* __restrict__ edges,
    const float* __restrict__ Wq, const float* __restrict__ Wk,
    const float* __restrict__ Wv, const float* __restrict__ Wev,
    float* __restrict__ P)
{
    __shared__ float As[16][36];    // 32 rows + pad
    __shared__ float Bs[16][68];    // 64 cols + pad
    int t = threadIdx.x;
    int rowT = blockIdx.x * 32;
    int jb = blockIdx.y;            // 0..15, 64-col tiles
    int colT = jb * 64;

    const float* W; int wbase; int nseg = 1;
    if (jb < 4)      { W = Wq; wbase = jb * 64; }
    else if (jb < 8) { W = Wk; wbase = (jb - 4) * 64; }
    else             { W = Wv; wbase = (jb - 8) * 64; nseg = 2; }

    int tm = t & 15, tn = t >> 4;   // rows tm*2.., cols tn*4..
    float acc[2][4];
    #pragma unroll
    for (int i = 0; i < 2; i++)
        #pragma unroll
        for (int j = 0; j < 4; j++) acc[i][j] = 0.f;

    int lrA = t >> 3;               // 0..31
    int lkA = (t & 7) * 2;          // 0..14
    int lrB = t >> 2;               // 0..63
    int lkB = (t & 3) * 4;          // 0..12

    for (int seg = 0; seg < nseg; ++seg) {
        const float* A  = (seg == 0) ? x : edges;
        const float* Wm = (seg == 0) ? W : Wev;
        for (int k0 = 0; k0 < DIMM; k0 += 16) {
            float2 av = *(const float2*)(A + (size_t)(rowT + lrA) * DIMM + k0 + lkA);
            As[lkA + 0][lrA] = av.x; As[lkA + 1][lrA] = av.y;
            float4 bv = *(const float4*)(Wm + (size_t)(wbase + lrB) * DIMM + k0 + lkB);
            Bs[lkB + 0][lrB] = bv.x; Bs[lkB + 1][lrB] = bv.y;
            Bs[lkB + 2][lrB] = bv.z; Bs[lkB + 3][lrB] = bv.w;
            __syncthreads();
            #pragma unroll
            for (int kk = 0; kk < 16; kk++) {
                float2 a2 = *(const float2*)&As[kk][tm * 2];
                float4 b4 = *(const float4*)&Bs[kk][tn * 4];
                float am[2] = {a2.x, a2.y};
                float bm[4] = {b4.x, b4.y, b4.z, b4.w};
                #pragma unroll
                for (int i = 0; i < 2; i++)
                    #pragma unroll
                    for (int j = 0; j < 4; j++) acc[i][j] += am[i] * bm[j];
            }
            __syncthreads();
        }
    }
    float sc = (jb >= 4 && jb < 8) ? SCALE_F : 1.0f;
    #pragma unroll
    for (int i = 0; i < 2; i++) {
        int r = rowT + tm * 2 + i;
        *(float4*)&P[(size_t)r * PW + colT + tn * 4] =
            make_float4(acc[i][0] * sc, acc[i][1] * sc, acc[i][2] * sc, acc[i][3] * sc);
    }
}

// ---------- colsum stage 1: partial[b][c] = sum over 16 rows of vv[.][c] ----------
__global__ __launch_bounds__(256) void colsum1_kernel(const float* __restrict__ P, float* __restrict__ partial) {
    int b = blockIdx.x;
    int t = threadIdx.x;
    int r0 = b * CS_ROWS;
    #pragma unroll
    for (int cg = 0; cg < 2; cg++) {
        int c = cg * 256 + t;
        float s = 0.f;
        #pragma unroll
        for (int r = 0; r < CS_ROWS; r++)
            s += P[(size_t)(r0 + r) * PW + 512 + c];
        partial[(size_t)b * VDIM + c] = s;
    }
}

// ---------- colsum stage 2: colsum[c] = sum_b partial[b][c] ----------
__global__ __launch_bounds__(512) void colsum2_kernel(const float* __restrict__ partial, float* __restrict__ colsum) {
    int c = threadIdx.x;  // 0..511
    float s = 0.f;
    for (int b = 0; b < CS_BLOCKS; b++) s += partial[(size_t)b * VDIM + c];
    colsum[c] = s;
}

// ---------- CSR build ----------
__global__ void hist_kernel(const int* __restrict__ ei32, const int* __restrict__ flag, int* __restrict__ deg) {
    int p = blockIdx.x * 256 + threadIdx.x;
    int is64 = flag[0];
    if (p < E_EDGES) atomicAdd(&deg[load_edge(ei32, is64, p)], 1);
}

__global__ __launch_bounds__(256) void scan_kernel(const int* __restrict__ deg, int* __restrict__ offs) {
    __shared__ int part[256];
    __shared__ int pref[257];
    int t = threadIdx.x;
    int base = t * 8;
    int s = 0;
    for (int i = 0; i < 8; i++) s += deg[base + i];
    part[t] = s;
    __syncthreads();
    if (t == 0) {
        int r = 0;
        for (int i = 0; i < 256; i++) { pref[i] = r; r += part[i]; }
        pref[256] = r;
    }
    __syncthreads();
    int run = pref[t];
    for (int i = 0; i < 8; i++) { offs[base + i] = run; run += deg[base + i]; }
    if (t == 0) offs[NN] = pref[256];
}

__global__ void fill_kernel(const int* __restrict__ ei32, const int* __restrict__ flag,
                            const int* __restrict__ offs, int* __restrict__ cursor,
                            int* __restrict__ edst, int* __restrict__ eid) {
    int p = blockIdx.x * 256 + threadIdx.x;
    int is64 = flag[0];
    if (p < E_EDGES) {
        int s = load_edge(ei32, is64, p);
        int pos = offs[s] + atomicAdd(&cursor[s], 1);
        edst[pos] = load_edge(ei32, is64, E_EDGES + p);
        eid[pos]  = p;
    }
}

// ---------- main: fused edge-dot + head-expand + softmax + Laplacian apply ----------
__global__ __launch_bounds__(256) void laplacian_kernel(
    const int* __restrict__ offs, const int* __restrict__ edst, const int* __restrict__ eid,
    const float* __restrict__ Wexp, const float* __restrict__ colsum,
    const float* __restrict__ P, float* __restrict__ out2)
{
    __shared__ int dstS[MAXD], idS[MAXD];
    __shared__ int dst2[MAXD], liveS[MAXD];
    __shared__ float ewS[MAXD][HEADS];
    __shared__ float aS[MAXD][EXPH];          // a -> exp -> normalized w (in place)
    __shared__ float WexpS[EXPH * HEADS];
    __shared__ float MeS[EXPH], rmaxS[EXPH], denomS[EXPH], wmaskS[EXPH];
    __shared__ int Dcnt;
    int n = blockIdx.x;
    int t = threadIdx.x;
    int o0 = offs[n], o1 = offs[n + 1];
    int dg = o1 - o0;
    if (dg > MAXD) dg = MAXD;  // Poisson(16): P(deg>128) ~ 0
    if (t == 0) Dcnt = 0;
    if (t < EXPH * HEADS) WexpS[t] = Wexp[t];
    if (t < dg) { dstS[t] = edst[o0 + t]; idS[t] = eid[o0 + t]; }
    __syncthreads();
    // parallel rank sort by edge id (ids unique -> rank is a permutation)
    if (t < dg) {
        int id = idS[t], d = dstS[t];
        int rank = 0;
        for (int j = 0; j < dg; j++) rank += (idS[j] < id) ? 1 : 0;
        dst2[rank] = d;
    }
    if (t < EXPH) {
        float s = 0.f;
        #pragma unroll
        for (int h = 0; h < HEADS; h++) s += MASKV * WexpS[t * HEADS + h];
        MeS[t] = s;
    }
    __syncthreads();
    // dedup: last write (max id = max rank) wins => live iff no later duplicate dst
    if (t < dg) {
        int d = dst2[t], live = 1;
        for (int j = t + 1; j < dg; j++)
            if (dst2[j] == d) { live = 0; break; }
        liveS[t] = live;
        if (live) atomicAdd(&Dcnt, 1);
    }
    // fused per-edge q.k dots (src == n for all edges of this block)
    {
        int h = t & 7;
        const float4* qr = (const float4*)(P + (size_t)n * PW + h * 32);
        for (int i = t >> 3; i < dg; i += 32) {
            const float4* kr = (const float4*)(P + (size_t)dst2[i] * PW + 256 + h * 32);
            float s = 0.f;
            #pragma unroll
            for (int m = 0; m < 8; m++) {
                float4 a = qr[m], b = kr[m];
                s += a.x * b.x + a.y * b.y + a.z * b.z + a.w * b.w;
            }
            ewS[i][h] = s;
        }
    }
    __syncthreads();
    // head-expand: a[i][e] = sum_h ew[i][h] * Wexp[e][h]
    for (int idx = t; idx < dg * EXPH; idx += 256) {
        int i = idx >> 4, e = idx & 15;
        float a = 0.f;
        #pragma unroll
        for (int hh = 0; hh < HEADS; hh++) a += ewS[i][hh] * WexpS[e * HEADS + hh];
        aS[i][e] = a;
    }
    __syncthreads();
    // row max per e
    if (t < EXPH) {
        int e = t;
        float rmax = MeS[e];
        for (int i = 0; i < dg; i++) if (liveS[i]) rmax = fmaxf(rmax, aS[i][e]);
        rmaxS[e] = rmax;
    }
    __syncthreads();
    // exps in parallel, in place
    for (int idx = t; idx < dg * EXPH; idx += 256) {
        int i = idx >> 4, e = idx & 15;
        aS[i][e] = liveS[i] ? expf(aS[i][e] - rmaxS[e]) : 0.f;
    }
    __syncthreads();
    int D = Dcnt;
    // denominator per e, deterministic sorted order
    if (t < EXPH) {
        int e = t;
        float wmE = expf(MeS[e] - rmaxS[e]);
        float denom = (float)(NN - D) * wmE;
        for (int i = 0; i < dg; i++) denom += aS[i][e];
        denomS[e] = denom;
        wmaskS[e] = wmE / denom;
    }
    __syncthreads();
    // normalize in parallel
    for (int idx = t; idx < dg * EXPH; idx += 256) {
        int i = idx >> 4, e = idx & 15;
        aS[i][e] = aS[i][e] / denomS[e];
    }
    __syncthreads();
    // out2[n][c] = vv[n][c] - wmask*colsum[c] + sum_live (wmask - w_i) * vv[dst_i][c]
    int e = t >> 4;
    float wm = wmaskS[e];
    const float2* vvn = (const float2*)(P + (size_t)n * PW + 512);
    const float2* cs2 = (const float2*)colsum;
    float2 v0 = vvn[t];
    float2 cv = cs2[t];
    float ax = v0.x - wm * cv.x;
    float ay = v0.y - wm * cv.y;
    for (int i = 0; i < dg; i++) {
        if (!liveS[i]) continue;
        float w = wm - aS[i][e];
        const float2* vr = (const float2*)(P + (size_t)dst2[i] * PW + 512);
        float2 vb = vr[t];
        ax += w * vb.x; ay += w * vb.y;
    }
    float2* o = (float2*)(out2 + (size_t)n * VDIM);
    o[t] = make_float2(ax, ay);
}

// ---------- final GEMM: C (2048x256) = out2 (2048x512) @ Wout^T (Wout 256x512) ----------
// tile: 16 rows x 64 cols, per-thread 1x4; grid (128,4) = 512 blocks
__global__ __launch_bounds__(256) void outgemm_kernel(
    const float* __restrict__ A, const float* __restrict__ W, float* __restrict__ C)
{
    __shared__ float As[16][20];
    __shared__ float Bs[16][68];
    int t = threadIdx.x;
    int rowT = blockIdx.x * 16;
    int colT = blockIdx.y * 64;
    int tm = t & 15, tn = t >> 4;
    float acc[4] = {0.f, 0.f, 0.f, 0.f};
    int lrA = t >> 4;               // 0..15 rows
    int lkA = t & 15;               // 0..15 k
    int lrB = t >> 2;               // 0..63
    int lkB = (t & 3) * 4;
    for (int k0 = 0; k0 < VDIM; k0 += 16) {
        As[lkA][lrA] = A[(size_t)(rowT + lrA) * VDIM + k0 + lkA];
        float4 bv = *(const float4*)(W + (size_t)(colT + lrB) * VDIM + k0 + lkB);
        Bs[lkB + 0][lrB] = bv.x; Bs[lkB + 1][lrB] = bv.y;
        Bs[lkB + 2][lrB] = bv.z; Bs[lkB + 3][lrB] = bv.w;
        __syncthreads();
        #pragma unroll
        for (int kk = 0; kk < 16; kk++) {
            float a = As[kk][tm];
            float4 b4 = *(const float4*)&Bs[kk][tn * 4];
            acc[0] += a * b4.x; acc[1] += a * b4.y;
            acc[2] += a * b4.z; acc[3] += a * b4.w;
        }
        __syncthreads();
    }
    int r = rowT + tm;
    *(float4*)&C[(size_t)r * DIMM + colT + tn * 4] =
        make_float4(acc[0], acc[1], acc[2], acc[3]);
}

extern "C" void kernel_launch(void* const* d_in, const int* in_sizes, int n_in,
                              void* d_out, int out_size, void* d_ws, size_t ws_size,
                              hipStream_t stream) {
    const float* x     = (const float*)d_in[0];
    const float* edges = (const float*)d_in[1];
    const int*   ei32  = (const int*)d_in[2];
    const float* Wq    = (const float*)d_in[3];
    const float* Wk    = (const float*)d_in[4];
    const float* Wv    = (const float*)d_in[5];
    const float* Wev   = (const float*)d_in[6];
    const float* Wexp  = (const float*)d_in[7];
    const float* Wout  = (const float*)d_in[8];
    float* out = (float*)d_out;

    char* ws = (char*)d_ws;
    size_t off = 0;
    auto alloc = [&](size_t bytes) -> void* {
        void* p = ws + off;
        off = (off + bytes + 255) & ~(size_t)255;
        return p;
    };
    float* P       = (float*)alloc((size_t)NN * PW * 4);          // 8 MB
    float* out2    = (float*)alloc((size_t)NN * VDIM * 4);        // 4 MB
    float* partial = (float*)alloc((size_t)CS_BLOCKS * VDIM * 4); // 256 KB
    float* colsum  = (float*)alloc(VDIM * 4);
    int* flag      = (int*)alloc(4);
    int* deg       = (int*)alloc(NN * 4);
    int* cursor    = (int*)alloc(NN * 4);
    int* offs      = (int*)alloc((NN + 1) * 4);
    int* edst      = (int*)alloc(E_EDGES * 4);
    int* eid       = (int*)alloc(E_EDGES * 4);
    (void)ws_size; (void)in_sizes; (void)n_in; (void)out_size;

    detect_init_kernel<<<9, 256, 0, stream>>>(ei32, flag, deg, cursor);
    proj_kernel<<<dim3(64, 16), 256, 0, stream>>>(x, edges, Wq, Wk, Wv, Wev, P);
    colsum1_kernel<<<CS_BLOCKS, 256, 0, stream>>>(P, partial);
    colsum2_kernel<<<1, 512, 0, stream>>>(partial, colsum);
    hist_kernel<<<E_EDGES / 256, 256, 0, stream>>>(ei32, flag, deg);
    scan_kernel<<<1, 256, 0, stream>>>(deg, offs);
    fill_kernel<<<E_EDGES / 256, 256, 0, stream>>>(ei32, flag, offs, cursor, edst, eid);
    laplacian_kernel<<<NN, 256, 0, stream>>>(offs, edst, eid, Wexp, colsum, P, out2);
    outgemm_kernel<<<dim3(128, 4), 256, 0, stream>>>(out2, Wout, out);
}

// Round 6
// 100.068 us; speedup vs baseline: 1.4746x; 1.2665x over previous
//
#include <hip/hip_runtime.h>

#define NN 2048
#define DIMM 256
#define HEADS 8
#define HEAD_DIM 32
#define EXPH 16
#define E_EDGES 32768
#define VDIM 512          // EXPH*HEAD_DIM
#define PW 1024           // P row width: [q 256 | k*scale 256 | vv 512]
#define SCALE_F 0.17677669529663687f
#define MASKV -1.0e9f
#define MAXD 128
#define CS_BLOCKS 128
#define CS_ROWS (NN / CS_BLOCKS)   // 16

typedef __attribute__((ext_vector_type(8))) short short8;
typedef __attribute__((ext_vector_type(4))) float f32x4;

__device__ __forceinline__ unsigned short f2bf(float f) {
    unsigned int u = __float_as_uint(f);
    unsigned int r = (u + 0x7FFFu + ((u >> 16) & 1u)) >> 16;   // RNE
    return (unsigned short)r;
}

// ---------- edge-index dtype detection + deg/cursor zero ----------
__global__ void detect_init_kernel(const int* __restrict__ ei32, int* __restrict__ flag,
                                   int* __restrict__ deg, int* __restrict__ cursor) {
    int b = blockIdx.x;
    int t = threadIdx.x;
    if (b == 0) {
        __shared__ int nz;
        if (t == 0) nz = 0;
        __syncthreads();
        if (ei32[2 * t + 1] != 0) atomicAdd(&nz, 1);
        __syncthreads();
        if (t == 0) flag[0] = (nz == 0) ? 1 : 0;  // 1 => int64
    } else {
        int idx = (b - 1) * 256 + t;  // blocks 1..8 cover 2048
        deg[idx] = 0;
        cursor[idx] = 0;
    }
}

__device__ __forceinline__ int load_edge(const int* __restrict__ ei32, int is64, int idx) {
    return is64 ? ei32[2 * idx] : ei32[idx];
}

// ---------- f32 -> bf16 conversion of x, edges, Wq, Wk, Wv, Wev, Wout ----------
// float4-unit regions (cumulative): x 131072 | edges 131072 | Wq 16384 | Wk 16384
//                                   | Wv 32768 | Wev 32768 | Wout 32768  => 393216
__global__ __launch_bounds__(256) void convert_kernel(
    const float* __restrict__ x, const float* __restrict__ edges,
    const float* __restrict__ Wq, const float* __restrict__ Wk,
    const float* __restrict__ Wv, const float* __restrict__ Wev,
    const float* __restrict__ Wout,
    unsigned short* __restrict__ xb, unsigned short* __restrict__ eb,
    unsigned short* __restrict__ Wqb, unsigned short* __restrict__ Wkb,
    unsigned short* __restrict__ Wvb, unsigned short* __restrict__ Wevb,
    unsigned short* __restrict__ Woutb)
{
    int idx = blockIdx.x * 256 + threadIdx.x;     // float4 index
    const float* src; unsigned short* dst; int loc;
    if      (idx < 131072) { src = x;     dst = xb;    loc = idx; }
    else if (idx < 262144) { src = edges; dst = eb;    loc = idx - 131072; }
    else if (idx < 278528) { src = Wq;    dst = Wqb;   loc = idx - 262144; }
    else if (idx < 294912) { src = Wk;    dst = Wkb;   loc = idx - 278528; }
    else if (idx < 327680) { src = Wv;    dst = Wvb;   loc = idx - 294912; }
    else if (idx < 360448) { src = Wev;   dst = Wevb;  loc = idx - 327680; }
    else                   { src = Wout;  dst = Woutb; loc = idx - 360448; }
    float4 v = *(const float4*)(src + (size_t)loc * 4);
    ushort4 o;
    o.x = f2bf(v.x); o.y = f2bf(v.y); o.z = f2bf(v.z); o.w = f2bf(v.w);
    *(ushort4*)(dst + (size_t)loc * 4) = o;
}

// ---------- projections via MFMA: P[n][0:256]=x@Wq^T ; [256:512]=x@Wk^T*SCALE ; [512:1024]=x@Wv^T+edges@Wev^T
// block tile 32x64, 4 waves (2x2), wave tile 16x32; no LDS, no barriers; grid (64,16)
__global__ __launch_bounds__(256) void proj_mfma_kernel(
    const unsigned short* __restrict__ xb, const unsigned short* __restrict__ eb,
    const unsigned short* __restrict__ Wqb, const unsigned short* __restrict__ Wkb,
    const unsigned short* __restrict__ Wvb, const unsigned short* __restrict__ Wevb,
    float* __restrict__ P)
{
    int t = threadIdx.x;
    int lane = t & 63;
    int wave = t >> 6;
    int wm = wave >> 1;     // 0..1
    int wn = wave & 1;      // 0..1
    int rowT = blockIdx.x * 32;
    int jb = blockIdx.y;    // 0..15 (64-col tiles of P)
    int colT = jb * 64;

    const unsigned short* Wb; int wbase; int nseg = 1;
    if (jb < 4)      { Wb = Wqb; wbase = jb * 64; }
    else if (jb < 8) { Wb = Wkb; wbase = (jb - 4) * 64; }
    else             { Wb = Wvb; wbase = (jb - 8) * 64; nseg = 2; }

    int arow = rowT + wm * 16 + (lane & 15);
    int koff = (lane >> 4) * 8;

    f32x4 acc0 = {0.f, 0.f, 0.f, 0.f};
    f32x4 acc1 = {0.f, 0.f, 0.f, 0.f};

    for (int seg = 0; seg < nseg; ++seg) {
        const unsigned short* Ab = (seg == 0) ? xb : eb;
        const unsigned short* Wm = (seg == 0) ? Wb : Wevb;
        const unsigned short* ap  = Ab + (size_t)arow * DIMM + koff;
        const unsigned short* b0p = Wm + (size_t)(wbase + wn * 32 + (lane & 15)) * DIMM + koff;
        const unsigned short* b1p = b0p + 16 * DIMM;
        #pragma unroll
        for (int ks = 0; ks < 8; ks++) {
            short8 af = *(const short8*)(ap  + ks * 32);
            short8 b0 = *(const short8*)(b0p + ks * 32);
            short8 b1 = *(const short8*)(b1p + ks * 32);
            acc0 = __builtin_amdgcn_mfma_f32_16x16x32_bf16(af, b0, acc0, 0, 0, 0);
            acc1 = __builtin_amdgcn_mfma_f32_16x16x32_bf16(af, b1, acc1, 0, 0, 0);
        }
    }
    float sc = (jb >= 4 && jb < 8) ? SCALE_F : 1.0f;
    int crow0 = rowT + wm * 16 + (lane >> 4) * 4;   // C/D: col=lane&15, row=(lane>>4)*4+r  [m89]
    int ccol  = colT + wn * 32 + (lane & 15);
    #pragma unroll
    for (int r = 0; r < 4; r++) {
        P[(size_t)(crow0 + r) * PW + ccol]      = acc0[r] * sc;
        P[(size_t)(crow0 + r) * PW + ccol + 16] = acc1[r] * sc;
    }
}

// ---------- colsum stage 1 ----------
__global__ __launch_bounds__(256) void colsum1_kernel(const float* __restrict__ P, float* __restrict__ partial) {
    int b = blockIdx.x;
    int t = threadIdx.x;
    int r0 = b * CS_ROWS;
    #pragma unroll
    for (int cg = 0; cg < 2; cg++) {
        int c = cg * 256 + t;
        float s = 0.f;
        #pragma unroll
        for (int r = 0; r < CS_ROWS; r++)
            s += P[(size_t)(r0 + r) * PW + 512 + c];
        partial[(size_t)b * VDIM + c] = s;
    }
}

// ---------- colsum stage 2 ----------
__global__ __launch_bounds__(512) void colsum2_kernel(const float* __restrict__ partial, float* __restrict__ colsum) {
    int c = threadIdx.x;
    float s = 0.f;
    for (int b = 0; b < CS_BLOCKS; b++) s += partial[(size_t)b * VDIM + c];
    colsum[c] = s;
}

// ---------- CSR build ----------
__global__ void hist_kernel(const int* __restrict__ ei32, const int* __restrict__ flag, int* __restrict__ deg) {
    int p = blockIdx.x * 256 + threadIdx.x;
    int is64 = flag[0];
    if (p < E_EDGES) atomicAdd(&deg[load_edge(ei32, is64, p)], 1);
}

__global__ __launch_bounds__(256) void scan_kernel(const int* __restrict__ deg, int* __restrict__ offs) {
    __shared__ int part[256];
    __shared__ int pref[257];
    int t = threadIdx.x;
    int base = t * 8;
    int s = 0;
    for (int i = 0; i < 8; i++) s += deg[base + i];
    part[t] = s;
    __syncthreads();
    if (t == 0) {
        int r = 0;
        for (int i = 0; i < 256; i++) { pref[i] = r; r += part[i]; }
        pref[256] = r;
    }
    __syncthreads();
    int run = pref[t];
    for (int i = 0; i < 8; i++) { offs[base + i] = run; run += deg[base + i]; }
    if (t == 0) offs[NN] = pref[256];
}

__global__ void fill_kernel(const int* __restrict__ ei32, const int* __restrict__ flag,
                            const int* __restrict__ offs, int* __restrict__ cursor,
                            int* __restrict__ edst, int* __restrict__ eid) {
    int p = blockIdx.x * 256 + threadIdx.x;
    int is64 = flag[0];
    if (p < E_EDGES) {
        int s = load_edge(ei32, is64, p);
        int pos = offs[s] + atomicAdd(&cursor[s], 1);
        edst[pos] = load_edge(ei32, is64, E_EDGES + p);
        eid[pos]  = p;
    }
}

// ---------- main: fused edge-dot + head-expand + softmax + Laplacian apply; bf16 out2 ----------
__global__ __launch_bounds__(256) void laplacian_kernel(
    const int* __restrict__ offs, const int* __restrict__ edst, const int* __restrict__ eid,
    const float* __restrict__ Wexp, const float* __restrict__ colsum,
    const float* __restrict__ P, unsigned short* __restrict__ out2b)
{
    __shared__ int dstS[MAXD], idS[MAXD];
    __shared__ int dst2[MAXD], liveS[MAXD];
    __shared__ float ewS[MAXD][HEADS];
    __shared__ float aS[MAXD][EXPH];
    __shared__ float WexpS[EXPH * HEADS];
    __shared__ float MeS[EXPH], rmaxS[EXPH], denomS[EXPH], wmaskS[EXPH];
    __shared__ int Dcnt;
    int n = blockIdx.x;
    int t = threadIdx.x;
    int o0 = offs[n], o1 = offs[n + 1];
    int dg = o1 - o0;
    if (dg > MAXD) dg = MAXD;
    if (t == 0) Dcnt = 0;
    if (t < EXPH * HEADS) WexpS[t] = Wexp[t];
    if (t < dg) { dstS[t] = edst[o0 + t]; idS[t] = eid[o0 + t]; }
    __syncthreads();
    if (t < dg) {
        int id = idS[t], d = dstS[t];
        int rank = 0;
        for (int j = 0; j < dg; j++) rank += (idS[j] < id) ? 1 : 0;
        dst2[rank] = d;
    }
    if (t < EXPH) {
        float s = 0.f;
        #pragma unroll
        for (int h = 0; h < HEADS; h++) s += MASKV * WexpS[t * HEADS + h];
        MeS[t] = s;
    }
    __syncthreads();
    if (t < dg) {
        int d = dst2[t], live = 1;
        for (int j = t + 1; j < dg; j++)
            if (dst2[j] == d) { live = 0; break; }
        liveS[t] = live;
        if (live) atomicAdd(&Dcnt, 1);
    }
    {
        int h = t & 7;
        const float4* qr = (const float4*)(P + (size_t)n * PW + h * 32);
        for (int i = t >> 3; i < dg; i += 32) {
            const float4* kr = (const float4*)(P + (size_t)dst2[i] * PW + 256 + h * 32);
            float s = 0.f;
            #pragma unroll
            for (int m = 0; m < 8; m++) {
                float4 a = qr[m], b = kr[m];
                s += a.x * b.x + a.y * b.y + a.z * b.z + a.w * b.w;
            }
            ewS[i][h] = s;
        }
    }
    __syncthreads();
    for (int idx = t; idx < dg * EXPH; idx += 256) {
        int i = idx >> 4, e = idx & 15;
        float a = 0.f;
        #pragma unroll
        for (int hh = 0; hh < HEADS; hh++) a += ewS[i][hh] * WexpS[e * HEADS + hh];
        aS[i][e] = a;
    }
    __syncthreads();
    if (t < EXPH) {
        int e = t;
        float rmax = MeS[e];
        for (int i = 0; i < dg; i++) if (liveS[i]) rmax = fmaxf(rmax, aS[i][e]);
        rmaxS[e] = rmax;
    }
    __syncthreads();
    for (int idx = t; idx < dg * EXPH; idx += 256) {
        int i = idx >> 4, e = idx & 15;
        aS[i][e] = liveS[i] ? expf(aS[i][e] - rmaxS[e]) : 0.f;
    }
    __syncthreads();
    int D = Dcnt;
    if (t < EXPH) {
        int e = t;
        float wmE = expf(MeS[e] - rmaxS[e]);
        float denom = (float)(NN - D) * wmE;
        for (int i = 0; i < dg; i++) denom += aS[i][e];
        denomS[e] = denom;
        wmaskS[e] = wmE / denom;
    }
    __syncthreads();
    for (int idx = t; idx < dg * EXPH; idx += 256) {
        int i = idx >> 4, e = idx & 15;
        aS[i][e] = aS[i][e] / denomS[e];
    }
    __syncthreads();
    int e = t >> 4;
    float wm = wmaskS[e];
    const float2* vvn = (const float2*)(P + (size_t)n * PW + 512);
    const float2* cs2 = (const float2*)colsum;
    float2 v0 = vvn[t];
    float2 cv = cs2[t];
    float ax = v0.x - wm * cv.x;
    float ay = v0.y - wm * cv.y;
    for (int i = 0; i < dg; i++) {
        if (!liveS[i]) continue;
        float w = wm - aS[i][e];
        const float2* vr = (const float2*)(P + (size_t)dst2[i] * PW + 512);
        float2 vb = vr[t];
        ax += w * vb.x; ay += w * vb.y;
    }
    unsigned int* o = (unsigned int*)(out2b + (size_t)n * VDIM);
    o[t] = (unsigned int)f2bf(ax) | ((unsigned int)f2bf(ay) << 16);
}

// ---------- final GEMM via MFMA: C (2048x256) = out2b (2048x512) @ Woutb^T ----------
// block tile 32x64, grid (64,4); K=512 -> 16 k-steps
__global__ __launch_bounds__(256) void outgemm_mfma_kernel(
    const unsigned short* __restrict__ Ab, const unsigned short* __restrict__ Wb,
    float* __restrict__ C)
{
    int t = threadIdx.x;
    int lane = t & 63;
    int wave = t >> 6;
    int wm = wave >> 1;
    int wn = wave & 1;
    int rowT = blockIdx.x * 32;
    int colT = blockIdx.y * 64;

    int arow = rowT + wm * 16 + (lane & 15);
    int koff = (lane >> 4) * 8;

    f32x4 acc0 = {0.f, 0.f, 0.f, 0.f};
    f32x4 acc1 = {0.f, 0.f, 0.f, 0.f};

    const unsigned short* ap  = Ab + (size_t)arow * VDIM + koff;
    const unsigned short* b0p = Wb + (size_t)(colT + wn * 32 + (lane & 15)) * VDIM + koff;
    const unsigned short* b1p = b0p + 16 * VDIM;
    #pragma unroll
    for (int ks = 0; ks < 16; ks++) {
        short8 af = *(const short8*)(ap  + ks * 32);
        short8 b0 = *(const short8*)(b0p + ks * 32);
        short8 b1 = *(const short8*)(b1p + ks * 32);
        acc0 = __builtin_amdgcn_mfma_f32_16x16x32_bf16(af, b0, acc0, 0, 0, 0);
        acc1 = __builtin_amdgcn_mfma_f32_16x16x32_bf16(af, b1, acc1, 0, 0, 0);
    }
    int crow0 = rowT + wm * 16 + (lane >> 4) * 4;
    int ccol  = colT + wn * 32 + (lane & 15);
    #pragma unroll
    for (int r = 0; r < 4; r++) {
        C[(size_t)(crow0 + r) * DIMM + ccol]      = acc0[r];
        C[(size_t)(crow0 + r) * DIMM + ccol + 16] = acc1[r];
    }
}

extern "C" void kernel_launch(void* const* d_in, const int* in_sizes, int n_in,
                              void* d_out, int out_size, void* d_ws, size_t ws_size,
                              hipStream_t stream) {
    const float* x     = (const float*)d_in[0];
    const float* edges = (const float*)d_in[1];
    const int*   ei32  = (const int*)d_in[2];
    const float* Wq    = (const float*)d_in[3];
    const float* Wk    = (const float*)d_in[4];
    const float* Wv    = (const float*)d_in[5];
    const float* Wev   = (const float*)d_in[6];
    const float* Wexp  = (const float*)d_in[7];
    const float* Wout  = (const float*)d_in[8];
    float* out = (float*)d_out;

    char* ws = (char*)d_ws;
    size_t off = 0;
    auto alloc = [&](size_t bytes) -> void* {
        void* p = ws + off;
        off = (off + bytes + 255) & ~(size_t)255;
        return p;
    };
    float* P        = (float*)alloc((size_t)NN * PW * 4);            // 8 MB
    float* partial  = (float*)alloc((size_t)CS_BLOCKS * VDIM * 4);   // 256 KB
    float* colsum   = (float*)alloc(VDIM * 4);
    unsigned short* xb    = (unsigned short*)alloc((size_t)NN * DIMM * 2);
    unsigned short* eb    = (unsigned short*)alloc((size_t)NN * DIMM * 2);
    unsigned short* Wqb   = (unsigned short*)alloc((size_t)DIMM * DIMM * 2);
    unsigned short* Wkb   = (unsigned short*)alloc((size_t)DIMM * DIMM * 2);
    unsigned short* Wvb   = (unsigned short*)alloc((size_t)VDIM * DIMM * 2);
    unsigned short* Wevb  = (unsigned short*)alloc((size_t)VDIM * DIMM * 2);
    unsigned short* Woutb = (unsigned short*)alloc((size_t)DIMM * VDIM * 2);
    unsigned short* out2b = (unsigned short*)alloc((size_t)NN * VDIM * 2);
    int* flag   = (int*)alloc(4);
    int* deg    = (int*)alloc(NN * 4);
    int* cursor = (int*)alloc(NN * 4);
    int* offs   = (int*)alloc((NN + 1) * 4);
    int* edst   = (int*)alloc(E_EDGES * 4);
    int* eid    = (int*)alloc(E_EDGES * 4);
    (void)ws_size; (void)in_sizes; (void)n_in; (void)out_size;

    detect_init_kernel<<<9, 256, 0, stream>>>(ei32, flag, deg, cursor);
    convert_kernel<<<1536, 256, 0, stream>>>(x, edges, Wq, Wk, Wv, Wev, Wout,
                                             xb, eb, Wqb, Wkb, Wvb, Wevb, Woutb);
    proj_mfma_kernel<<<dim3(64, 16), 256, 0, stream>>>(xb, eb, Wqb, Wkb, Wvb, Wevb, P);
    colsum1_kernel<<<CS_BLOCKS, 256, 0, stream>>>(P, partial);
    colsum2_kernel<<<1, 512, 0, stream>>>(partial, colsum);
    hist_kernel<<<E_EDGES / 256, 256, 0, stream>>>(ei32, flag, deg);
    scan_kernel<<<1, 256, 0, stream>>>(deg, offs);
    fill_kernel<<<E_EDGES / 256, 256, 0, stream>>>(ei32, flag, offs, cursor, edst, eid);
    laplacian_kernel<<<NN, 256, 0, stream>>>(offs, edst, eid, Wexp, colsum, P, out2b);
    outgemm_mfma_kernel<<<dim3(64, 4), 256, 0, stream>>>(out2b, Woutb, out);
}

// Round 7
// 90.189 us; speedup vs baseline: 1.6361x; 1.1095x over previous
//
#include <hip/hip_runtime.h>

#define NN 2048
#define DIMM 256
#define HEADS 8
#define HEAD_DIM 32
#define EXPH 16
#define E_EDGES 32768
#define VDIM 512          // EXPH*HEAD_DIM
#define PW 1024           // P row width in bf16: [q 256 | k*scale 256 | vv 512]
#define SCALE_F 0.17677669529663687f
#define MASKV -1.0e9f
#define MAXD 128
#define CS_BLOCKS 128
#define CS_ROWS (NN / CS_BLOCKS)   // 16

typedef __attribute__((ext_vector_type(8))) short short8;
typedef __attribute__((ext_vector_type(4))) float f32x4;

__device__ __forceinline__ unsigned short f2bf(float f) {
    unsigned int u = __float_as_uint(f);
    unsigned int r = (u + 0x7FFFu + ((u >> 16) & 1u)) >> 16;   // RNE
    return (unsigned short)r;
}
__device__ __forceinline__ float bflo(unsigned int u) { return __uint_as_float(u << 16); }
__device__ __forceinline__ float bfhi(unsigned int u) { return __uint_as_float(u & 0xFFFF0000u); }

__device__ __forceinline__ int load_edge(const int* __restrict__ ei32, int is64, int idx) {
    return is64 ? ei32[2 * idx] : ei32[idx];
}

// ---------- f32 -> bf16 convert of inputs + deg/cursor zero (blocks 1536..1543) ----------
// float4-unit regions (cumulative): x 131072 | edges 131072 | Wq 16384 | Wk 16384
//                                   | Wv 32768 | Wev 32768 | Wout 32768  => 393216 (1536 blocks)
__global__ __launch_bounds__(256) void convert_init_kernel(
    const float* __restrict__ x, const float* __restrict__ edges,
    const float* __restrict__ Wq, const float* __restrict__ Wk,
    const float* __restrict__ Wv, const float* __restrict__ Wev,
    const float* __restrict__ Wout,
    unsigned short* __restrict__ xb, unsigned short* __restrict__ eb,
    unsigned short* __restrict__ Wqb, unsigned short* __restrict__ Wkb,
    unsigned short* __restrict__ Wvb, unsigned short* __restrict__ Wevb,
    unsigned short* __restrict__ Woutb,
    int* __restrict__ deg, int* __restrict__ cursor)
{
    int b = blockIdx.x;
    int t = threadIdx.x;
    if (b >= 1536) {
        int idx = (b - 1536) * 256 + t;   // 8 blocks cover 2048
        deg[idx] = 0;
        cursor[idx] = 0;
        return;
    }
    int idx = b * 256 + t;                // float4 index
    const float* src; unsigned short* dst; int loc;
    if      (idx < 131072) { src = x;     dst = xb;    loc = idx; }
    else if (idx < 262144) { src = edges; dst = eb;    loc = idx - 131072; }
    else if (idx < 278528) { src = Wq;    dst = Wqb;   loc = idx - 262144; }
    else if (idx < 294912) { src = Wk;    dst = Wkb;   loc = idx - 278528; }
    else if (idx < 327680) { src = Wv;    dst = Wvb;   loc = idx - 294912; }
    else if (idx < 360448) { src = Wev;   dst = Wevb;  loc = idx - 327680; }
    else                   { src = Wout;  dst = Woutb; loc = idx - 360448; }
    float4 v = *(const float4*)(src + (size_t)loc * 4);
    ushort4 o;
    o.x = f2bf(v.x); o.y = f2bf(v.y); o.z = f2bf(v.z); o.w = f2bf(v.w);
    *(ushort4*)(dst + (size_t)loc * 4) = o;
}

// ---------- projections via MFMA -> bf16 P ----------
// block tile 32x64, 4 waves (2x2), wave tile 16x32; no LDS/barriers; grid (64,16)
__global__ __launch_bounds__(256) void proj_mfma_kernel(
    const unsigned short* __restrict__ xb, const unsigned short* __restrict__ eb,
    const unsigned short* __restrict__ Wqb, const unsigned short* __restrict__ Wkb,
    const unsigned short* __restrict__ Wvb, const unsigned short* __restrict__ Wevb,
    unsigned short* __restrict__ Pb)
{
    int t = threadIdx.x;
    int lane = t & 63;
    int wave = t >> 6;
    int wm = wave >> 1;
    int wn = wave & 1;
    int rowT = blockIdx.x * 32;
    int jb = blockIdx.y;    // 0..15 (64-col tiles of P)
    int colT = jb * 64;

    const unsigned short* Wb; int wbase; int nseg = 1;
    if (jb < 4)      { Wb = Wqb; wbase = jb * 64; }
    else if (jb < 8) { Wb = Wkb; wbase = (jb - 4) * 64; }
    else             { Wb = Wvb; wbase = (jb - 8) * 64; nseg = 2; }

    int arow = rowT + wm * 16 + (lane & 15);
    int koff = (lane >> 4) * 8;

    f32x4 acc0 = {0.f, 0.f, 0.f, 0.f};
    f32x4 acc1 = {0.f, 0.f, 0.f, 0.f};

    for (int seg = 0; seg < nseg; ++seg) {
        const unsigned short* Ab = (seg == 0) ? xb : eb;
        const unsigned short* Wm = (seg == 0) ? Wb : Wevb;
        const unsigned short* ap  = Ab + (size_t)arow * DIMM + koff;
        const unsigned short* b0p = Wm + (size_t)(wbase + wn * 32 + (lane & 15)) * DIMM + koff;
        const unsigned short* b1p = b0p + 16 * DIMM;
        #pragma unroll
        for (int ks = 0; ks < 8; ks++) {
            short8 af = *(const short8*)(ap  + ks * 32);
            short8 b0 = *(const short8*)(b0p + ks * 32);
            short8 b1 = *(const short8*)(b1p + ks * 32);
            acc0 = __builtin_amdgcn_mfma_f32_16x16x32_bf16(af, b0, acc0, 0, 0, 0);
            acc1 = __builtin_amdgcn_mfma_f32_16x16x32_bf16(af, b1, acc1, 0, 0, 0);
        }
    }
    float sc = (jb >= 4 && jb < 8) ? SCALE_F : 1.0f;
    int crow0 = rowT + wm * 16 + (lane >> 4) * 4;   // C/D: col=lane&15, row=(lane>>4)*4+r
    int ccol  = colT + wn * 32 + (lane & 15);
    #pragma unroll
    for (int r = 0; r < 4; r++) {
        Pb[(size_t)(crow0 + r) * PW + ccol]      = f2bf(acc0[r] * sc);
        Pb[(size_t)(crow0 + r) * PW + ccol + 16] = f2bf(acc1[r] * sc);
    }
}

// ---------- colsum stage 1 (bf16 vv) + edge histogram, merged; grid 128 ----------
__global__ __launch_bounds__(256) void colsum1_hist_kernel(
    const unsigned short* __restrict__ Pb, float* __restrict__ partial,
    const int* __restrict__ ei32, int* __restrict__ deg)
{
    int b = blockIdx.x;
    int t = threadIdx.x;
    // per-block dtype detection: high words of first 256 int64s all zero <=> int64
    int nz = __syncthreads_count(ei32[2 * t + 1] != 0);
    int is64 = (nz == 0);
    atomicAdd(&deg[load_edge(ei32, is64, b * 256 + t)], 1);
    // column sums over 16 rows, 2 adjacent cols per thread
    int r0 = b * CS_ROWS;
    float sx = 0.f, sy = 0.f;
    #pragma unroll
    for (int r = 0; r < CS_ROWS; r++) {
        unsigned int u = ((const unsigned int*)(Pb + (size_t)(r0 + r) * PW + 512))[t];
        sx += bflo(u); sy += bfhi(u);
    }
    partial[(size_t)b * VDIM + 2 * t]     = sx;
    partial[(size_t)b * VDIM + 2 * t + 1] = sy;
}

// ---------- scan + colsum stage 2, merged; 1 block x 512 ----------
__global__ __launch_bounds__(512) void scan_colsum2_kernel(
    const int* __restrict__ deg, int* __restrict__ offs,
    const float* __restrict__ partial, float* __restrict__ colsum)
{
    int t = threadIdx.x;
    // colsum2: all 512 threads
    {
        float s = 0.f;
        for (int b = 0; b < CS_BLOCKS; b++) s += partial[(size_t)b * VDIM + t];
        colsum[t] = s;
    }
    // scan: threads 0..255, barriers unconditional
    __shared__ int part[256];
    __shared__ int pref[257];
    int base = (t < 256) ? t * 8 : 0;
    if (t < 256) {
        int s = 0;
        for (int i = 0; i < 8; i++) s += deg[base + i];
        part[t] = s;
    }
    __syncthreads();
    if (t == 0) {
        int r = 0;
        for (int i = 0; i < 256; i++) { pref[i] = r; r += part[i]; }
        pref[256] = r;
    }
    __syncthreads();
    if (t < 256) {
        int run = pref[t];
        for (int i = 0; i < 8; i++) { offs[base + i] = run; run += deg[base + i]; }
    }
    if (t == 0) offs[NN] = pref[256];
}

// ---------- CSR fill; grid 128 ----------
__global__ __launch_bounds__(256) void fill_kernel(
    const int* __restrict__ ei32, const int* __restrict__ offs,
    int* __restrict__ cursor, int* __restrict__ edst, int* __restrict__ eid)
{
    int t = threadIdx.x;
    int nz = __syncthreads_count(ei32[2 * t + 1] != 0);
    int is64 = (nz == 0);
    int p = blockIdx.x * 256 + t;
    int s = load_edge(ei32, is64, p);
    int pos = offs[s] + atomicAdd(&cursor[s], 1);
    edst[pos] = load_edge(ei32, is64, E_EDGES + p);
    eid[pos]  = p;
}

// ---------- main: fused edge-dot + head-expand + softmax + Laplacian apply (bf16 P) ----------
__global__ __launch_bounds__(256) void laplacian_kernel(
    const int* __restrict__ offs, const int* __restrict__ edst, const int* __restrict__ eid,
    const float* __restrict__ Wexp, const float* __restrict__ colsum,
    const unsigned short* __restrict__ Pb, unsigned short* __restrict__ out2b)
{
    __shared__ int dstS[MAXD], idS[MAXD];
    __shared__ int dst2[MAXD], liveS[MAXD];
    __shared__ float ewS[MAXD][HEADS];
    __shared__ float aS[MAXD][EXPH];
    __shared__ float WexpS[EXPH * HEADS];
    __shared__ float qS[DIMM];
    __shared__ float MeS[EXPH], rmaxS[EXPH], denomS[EXPH], wmaskS[EXPH];
    __shared__ int Dcnt;
    int n = blockIdx.x;
    int t = threadIdx.x;
    int o0 = offs[n], o1 = offs[n + 1];
    int dg = o1 - o0;
    if (dg > MAXD) dg = MAXD;
    if (t == 0) Dcnt = 0;
    if (t < EXPH * HEADS) WexpS[t] = Wexp[t];
    if (t < dg) { dstS[t] = edst[o0 + t]; idS[t] = eid[o0 + t]; }
    // stage own q row as f32
    if (t < 128) {
        unsigned int u = ((const unsigned int*)(Pb + (size_t)n * PW))[t];
        qS[2 * t]     = bflo(u);
        qS[2 * t + 1] = bfhi(u);
    }
    __syncthreads();
    // parallel rank sort by edge id
    if (t < dg) {
        int id = idS[t], d = dstS[t];
        int rank = 0;
        for (int j = 0; j < dg; j++) rank += (idS[j] < id) ? 1 : 0;
        dst2[rank] = d;
    }
    if (t < EXPH) {
        float s = 0.f;
        #pragma unroll
        for (int h = 0; h < HEADS; h++) s += MASKV * WexpS[t * HEADS + h];
        MeS[t] = s;
    }
    __syncthreads();
    // dedup: last write (max rank) wins
    if (t < dg) {
        int d = dst2[t], live = 1;
        for (int j = t + 1; j < dg; j++)
            if (dst2[j] == d) { live = 0; break; }
        liveS[t] = live;
        if (live) atomicAdd(&Dcnt, 1);
    }
    // per-edge q.k dots: 8 lanes per edge, 32 bf16 each
    {
        int h = t & 7;
        const float* qh = qS + h * 32;
        for (int i = t >> 3; i < dg; i += 32) {
            const uint4* kr = (const uint4*)(Pb + (size_t)dst2[i] * PW + 256 + h * 32);
            float s = 0.f;
            #pragma unroll
            for (int m = 0; m < 4; m++) {
                uint4 u = kr[m];
                const float* qq = qh + m * 8;
                s += qq[0] * bflo(u.x) + qq[1] * bfhi(u.x)
                   + qq[2] * bflo(u.y) + qq[3] * bfhi(u.y)
                   + qq[4] * bflo(u.z) + qq[5] * bfhi(u.z)
                   + qq[6] * bflo(u.w) + qq[7] * bfhi(u.w);
            }
            ewS[i][h] = s;
        }
    }
    __syncthreads();
    // head-expand
    for (int idx = t; idx < dg * EXPH; idx += 256) {
        int i = idx >> 4, e = idx & 15;
        float a = 0.f;
        #pragma unroll
        for (int hh = 0; hh < HEADS; hh++) a += ewS[i][hh] * WexpS[e * HEADS + hh];
        aS[i][e] = a;
    }
    __syncthreads();
    if (t < EXPH) {
        int e = t;
        float rmax = MeS[e];
        for (int i = 0; i < dg; i++) if (liveS[i]) rmax = fmaxf(rmax, aS[i][e]);
        rmaxS[e] = rmax;
    }
    __syncthreads();
    for (int idx = t; idx < dg * EXPH; idx += 256) {
        int i = idx >> 4, e = idx & 15;
        aS[i][e] = liveS[i] ? expf(aS[i][e] - rmaxS[e]) : 0.f;
    }
    __syncthreads();
    int D = Dcnt;
    if (t < EXPH) {
        int e = t;
        float wmE = expf(MeS[e] - rmaxS[e]);
        float denom = (float)(NN - D) * wmE;
        for (int i = 0; i < dg; i++) denom += aS[i][e];
        denomS[e] = denom;
        wmaskS[e] = wmE / denom;
    }
    __syncthreads();
    for (int idx = t; idx < dg * EXPH; idx += 256) {
        int i = idx >> 4, e = idx & 15;
        aS[i][e] = aS[i][e] / denomS[e];
    }
    __syncthreads();
    // out2[n][c] = vv[n][c] - wmask*colsum[c] + sum_live (wmask - w_i) * vv[dst_i][c]
    int e = t >> 4;
    float wm = wmaskS[e];
    unsigned int uv = ((const unsigned int*)(Pb + (size_t)n * PW + 512))[t];
    float2 cv = ((const float2*)colsum)[t];
    float ax = bflo(uv) - wm * cv.x;
    float ay = bfhi(uv) - wm * cv.y;
    for (int i = 0; i < dg; i++) {
        if (!liveS[i]) continue;
        float w = wm - aS[i][e];
        unsigned int ub = ((const unsigned int*)(Pb + (size_t)dst2[i] * PW + 512))[t];
        ax += w * bflo(ub);
        ay += w * bfhi(ub);
    }
    unsigned int* o = (unsigned int*)(out2b + (size_t)n * VDIM);
    o[t] = (unsigned int)f2bf(ax) | ((unsigned int)f2bf(ay) << 16);
}

// ---------- final GEMM via MFMA: C (2048x256) = out2b (2048x512) @ Woutb^T ----------
__global__ __launch_bounds__(256) void outgemm_mfma_kernel(
    const unsigned short* __restrict__ Ab, const unsigned short* __restrict__ Wb,
    float* __restrict__ C)
{
    int t = threadIdx.x;
    int lane = t & 63;
    int wave = t >> 6;
    int wm = wave >> 1;
    int wn = wave & 1;
    int rowT = blockIdx.x * 32;
    int colT = blockIdx.y * 64;

    int arow = rowT + wm * 16 + (lane & 15);
    int koff = (lane >> 4) * 8;

    f32x4 acc0 = {0.f, 0.f, 0.f, 0.f};
    f32x4 acc1 = {0.f, 0.f, 0.f, 0.f};

    const unsigned short* ap  = Ab + (size_t)arow * VDIM + koff;
    const unsigned short* b0p = Wb + (size_t)(colT + wn * 32 + (lane & 15)) * VDIM + koff;
    const unsigned short* b1p = b0p + 16 * VDIM;
    #pragma unroll
    for (int ks = 0; ks < 16; ks++) {
        short8 af = *(const short8*)(ap  + ks * 32);
        short8 b0 = *(const short8*)(b0p + ks * 32);
        short8 b1 = *(const short8*)(b1p + ks * 32);
        acc0 = __builtin_amdgcn_mfma_f32_16x16x32_bf16(af, b0, acc0, 0, 0, 0);
        acc1 = __builtin_amdgcn_mfma_f32_16x16x32_bf16(af, b1, acc1, 0, 0, 0);
    }
    int crow0 = rowT + wm * 16 + (lane >> 4) * 4;
    int ccol  = colT + wn * 32 + (lane & 15);
    #pragma unroll
    for (int r = 0; r < 4; r++) {
        C[(size_t)(crow0 + r) * DIMM + ccol]      = acc0[r];
        C[(size_t)(crow0 + r) * DIMM + ccol + 16] = acc1[r];
    }
}

extern "C" void kernel_launch(void* const* d_in, const int* in_sizes, int n_in,
                              void* d_out, int out_size, void* d_ws, size_t ws_size,
                              hipStream_t stream) {
    const float* x     = (const float*)d_in[0];
    const float* edges = (const float*)d_in[1];
    const int*   ei32  = (const int*)d_in[2];
    const float* Wq    = (const float*)d_in[3];
    const float* Wk    = (const float*)d_in[4];
    const float* Wv    = (const float*)d_in[5];
    const float* Wev   = (const float*)d_in[6];
    const float* Wexp  = (const float*)d_in[7];
    const float* Wout  = (const float*)d_in[8];
    float* out = (float*)d_out;

    char* ws = (char*)d_ws;
    size_t off = 0;
    auto alloc = [&](size_t bytes) -> void* {
        void* p = ws + off;
        off = (off + bytes + 255) & ~(size_t)255;
        return p;
    };
    unsigned short* Pb    = (unsigned short*)alloc((size_t)NN * PW * 2);   // 4 MB
    float* partial        = (float*)alloc((size_t)CS_BLOCKS * VDIM * 4);   // 256 KB
    float* colsum         = (float*)alloc(VDIM * 4);
    unsigned short* xb    = (unsigned short*)alloc((size_t)NN * DIMM * 2);
    unsigned short* eb    = (unsigned short*)alloc((size_t)NN * DIMM * 2);
    unsigned short* Wqb   = (unsigned short*)alloc((size_t)DIMM * DIMM * 2);
    unsigned short* Wkb   = (unsigned short*)alloc((size_t)DIMM * DIMM * 2);
    unsigned short* Wvb   = (unsigned short*)alloc((size_t)VDIM * DIMM * 2);
    unsigned short* Wevb  = (unsigned short*)alloc((size_t)VDIM * DIMM * 2);
    unsigned short* Woutb = (unsigned short*)alloc((size_t)DIMM * VDIM * 2);
    unsigned short* out2b = (unsigned short*)alloc((size_t)NN * VDIM * 2);
    int* deg    = (int*)alloc(NN * 4);
    int* cursor = (int*)alloc(NN * 4);
    int* offs   = (int*)alloc((NN + 1) * 4);
    int* edst   = (int*)alloc(E_EDGES * 4);
    int* eid    = (int*)alloc(E_EDGES * 4);
    (void)ws_size; (void)in_sizes; (void)n_in; (void)out_size;

    convert_init_kernel<<<1544, 256, 0, stream>>>(x, edges, Wq, Wk, Wv, Wev, Wout,
                                                  xb, eb, Wqb, Wkb, Wvb, Wevb, Woutb,
                                                  deg, cursor);
    proj_mfma_kernel<<<dim3(64, 16), 256, 0, stream>>>(xb, eb, Wqb, Wkb, Wvb, Wevb, Pb);
    colsum1_hist_kernel<<<CS_BLOCKS, 256, 0, stream>>>(Pb, partial, ei32, deg);
    scan_colsum2_kernel<<<1, 512, 0, stream>>>(deg, offs, partial, colsum);
    fill_kernel<<<E_EDGES / 256, 256, 0, stream>>>(ei32, offs, cursor, edst, eid);
    laplacian_kernel<<<NN, 256, 0, stream>>>(offs, edst, eid, Wexp, colsum, Pb, out2b);
    outgemm_mfma_kernel<<<dim3(64, 4), 256, 0, stream>>>(out2b, Woutb, out);
}

// Round 8
// 70.499 us; speedup vs baseline: 2.0931x; 1.2793x over previous
//
#include <hip/hip_runtime.h>

#define NN 2048
#define DIMM 256
#define HEADS 8
#define HEAD_DIM 32
#define EXPH 16
#define E_EDGES 32768
#define VDIM 512          // EXPH*HEAD_DIM
#define PW 1024           // P row width in bf16: [q 256 | k*scale 256 | vv 512]
#define SCALE_F 0.17677669529663687f
#define MASKV -1.0e9f
#define SLOTW 64          // max edges per src (Poisson mean 16; P(>64) ~ 1e-18)
#define CS_BLOCKS 128
#define CS_ROWS (NN / CS_BLOCKS)   // 16

typedef __attribute__((ext_vector_type(8))) short short8;
typedef __attribute__((ext_vector_type(4))) float f32x4;

__device__ __forceinline__ unsigned short f2bf(float f) {
    unsigned int u = __float_as_uint(f);
    unsigned int r = (u + 0x7FFFu + ((u >> 16) & 1u)) >> 16;   // RNE
    return (unsigned short)r;
}
__device__ __forceinline__ float bflo(unsigned int u) { return __uint_as_float(u << 16); }
__device__ __forceinline__ float bfhi(unsigned int u) { return __uint_as_float(u & 0xFFFF0000u); }

__device__ __forceinline__ int load_edge(const int* __restrict__ ei32, int is64, int idx) {
    return is64 ? ei32[2 * idx] : ei32[idx];
}

// ---------- f32 -> bf16 convert of inputs + slotCnt zero (blocks 1536..1543) ----------
// float4-unit regions (cumulative): x 131072 | edges 131072 | Wq 16384 | Wk 16384
//                                   | Wv 32768 | Wev 32768 | Wout 32768  => 393216 (1536 blocks)
__global__ __launch_bounds__(256) void convert_init_kernel(
    const float* __restrict__ x, const float* __restrict__ edges,
    const float* __restrict__ Wq, const float* __restrict__ Wk,
    const float* __restrict__ Wv, const float* __restrict__ Wev,
    const float* __restrict__ Wout,
    unsigned short* __restrict__ xb, unsigned short* __restrict__ eb,
    unsigned short* __restrict__ Wqb, unsigned short* __restrict__ Wkb,
    unsigned short* __restrict__ Wvb, unsigned short* __restrict__ Wevb,
    unsigned short* __restrict__ Woutb,
    int* __restrict__ slotCnt)
{
    int b = blockIdx.x;
    int t = threadIdx.x;
    if (b >= 1536) {
        slotCnt[(b - 1536) * 256 + t] = 0;   // 8 blocks cover 2048
        return;
    }
    int idx = b * 256 + t;                // float4 index
    const float* src; unsigned short* dst; int loc;
    if      (idx < 131072) { src = x;     dst = xb;    loc = idx; }
    else if (idx < 262144) { src = edges; dst = eb;    loc = idx - 131072; }
    else if (idx < 278528) { src = Wq;    dst = Wqb;   loc = idx - 262144; }
    else if (idx < 294912) { src = Wk;    dst = Wkb;   loc = idx - 278528; }
    else if (idx < 327680) { src = Wv;    dst = Wvb;   loc = idx - 294912; }
    else if (idx < 360448) { src = Wev;   dst = Wevb;  loc = idx - 327680; }
    else                   { src = Wout;  dst = Woutb; loc = idx - 360448; }
    float4 v = *(const float4*)(src + (size_t)loc * 4);
    ushort4 o;
    o.x = f2bf(v.x); o.y = f2bf(v.y); o.z = f2bf(v.z); o.w = f2bf(v.w);
    *(ushort4*)(dst + (size_t)loc * 4) = o;
}

// ---------- projections via MFMA -> bf16 P ----------
// block tile 32x64, 4 waves (2x2), wave tile 16x32; no LDS/barriers; grid (64,16)
__global__ __launch_bounds__(256) void proj_mfma_kernel(
    const unsigned short* __restrict__ xb, const unsigned short* __restrict__ eb,
    const unsigned short* __restrict__ Wqb, const unsigned short* __restrict__ Wkb,
    const unsigned short* __restrict__ Wvb, const unsigned short* __restrict__ Wevb,
    unsigned short* __restrict__ Pb)
{
    int t = threadIdx.x;
    int lane = t & 63;
    int wave = t >> 6;
    int wm = wave >> 1;
    int wn = wave & 1;
    int rowT = blockIdx.x * 32;
    int jb = blockIdx.y;    // 0..15 (64-col tiles of P)
    int colT = jb * 64;

    const unsigned short* Wb; int wbase; int nseg = 1;
    if (jb < 4)      { Wb = Wqb; wbase = jb * 64; }
    else if (jb < 8) { Wb = Wkb; wbase = (jb - 4) * 64; }
    else             { Wb = Wvb; wbase = (jb - 8) * 64; nseg = 2; }

    int arow = rowT + wm * 16 + (lane & 15);
    int koff = (lane >> 4) * 8;

    f32x4 acc0 = {0.f, 0.f, 0.f, 0.f};
    f32x4 acc1 = {0.f, 0.f, 0.f, 0.f};

    for (int seg = 0; seg < nseg; ++seg) {
        const unsigned short* Ab = (seg == 0) ? xb : eb;
        const unsigned short* Wm = (seg == 0) ? Wb : Wevb;
        const unsigned short* ap  = Ab + (size_t)arow * DIMM + koff;
        const unsigned short* b0p = Wm + (size_t)(wbase + wn * 32 + (lane & 15)) * DIMM + koff;
        const unsigned short* b1p = b0p + 16 * DIMM;
        #pragma unroll
        for (int ks = 0; ks < 8; ks++) {
            short8 af = *(const short8*)(ap  + ks * 32);
            short8 b0 = *(const short8*)(b0p + ks * 32);
            short8 b1 = *(const short8*)(b1p + ks * 32);
            acc0 = __builtin_amdgcn_mfma_f32_16x16x32_bf16(af, b0, acc0, 0, 0, 0);
            acc1 = __builtin_amdgcn_mfma_f32_16x16x32_bf16(af, b1, acc1, 0, 0, 0);
        }
    }
    float sc = (jb >= 4 && jb < 8) ? SCALE_F : 1.0f;
    int crow0 = rowT + wm * 16 + (lane >> 4) * 4;   // C/D: col=lane&15, row=(lane>>4)*4+r
    int ccol  = colT + wn * 32 + (lane & 15);
    #pragma unroll
    for (int r = 0; r < 4; r++) {
        Pb[(size_t)(crow0 + r) * PW + ccol]      = f2bf(acc0[r] * sc);
        Pb[(size_t)(crow0 + r) * PW + ccol + 16] = f2bf(acc1[r] * sc);
    }
}

// ---------- colsum stage 1 (bf16 vv) + slot scatter, merged; grid 128 ----------
__global__ __launch_bounds__(256) void colsum1_scatter_kernel(
    const unsigned short* __restrict__ Pb, float* __restrict__ partial,
    const int* __restrict__ ei32, int* __restrict__ slotCnt,
    unsigned int* __restrict__ slots)
{
    int b = blockIdx.x;
    int t = threadIdx.x;
    // per-block dtype detection: high words of first 256 int64s all zero <=> int64
    int nz = __syncthreads_count(ei32[2 * t + 1] != 0);
    int is64 = (nz == 0);
    int p = b * 256 + t;
    int s = load_edge(ei32, is64, p);
    int d = load_edge(ei32, is64, E_EDGES + p);
    int pos = atomicAdd(&slotCnt[s], 1);
    if (pos < SLOTW)
        slots[(size_t)s * SLOTW + pos] = (unsigned int)(p * 2048 + d);  // id in high bits
    // column sums over 16 rows, 2 adjacent cols per thread
    int r0 = b * CS_ROWS;
    float sx = 0.f, sy = 0.f;
    #pragma unroll
    for (int r = 0; r < CS_ROWS; r++) {
        unsigned int u = ((const unsigned int*)(Pb + (size_t)(r0 + r) * PW + 512))[t];
        sx += bflo(u); sy += bfhi(u);
    }
    partial[(size_t)b * VDIM + 2 * t]     = sx;
    partial[(size_t)b * VDIM + 2 * t + 1] = sy;
}

// ---------- colsum stage 2; 1 block x 512 ----------
__global__ __launch_bounds__(512) void colsum2_kernel(
    const float* __restrict__ partial, float* __restrict__ colsum)
{
    int t = threadIdx.x;
    float s = 0.f;
    for (int b = 0; b < CS_BLOCKS; b++) s += partial[(size_t)b * VDIM + t];
    colsum[t] = s;
}

// ---------- main: fused edge-dot + head-expand + softmax + Laplacian apply (bf16 P, slots) ----------
__global__ __launch_bounds__(256) void laplacian_kernel(
    const int* __restrict__ slotCnt, const unsigned int* __restrict__ slots,
    const float* __restrict__ Wexp, const float* __restrict__ colsum,
    const unsigned short* __restrict__ Pb, unsigned short* __restrict__ out2b)
{
    __shared__ unsigned int pkS[SLOTW], srtS[SLOTW];
    __shared__ int liveS[SLOTW];
    __shared__ float ewS[SLOTW][HEADS];
    __shared__ float aS[SLOTW][EXPH];
    __shared__ float WexpS[EXPH * HEADS];
    __shared__ float qS[DIMM];
    __shared__ float MeS[EXPH], rmaxS[EXPH], denomS[EXPH], wmaskS[EXPH];
    __shared__ int Dcnt;
    int n = blockIdx.x;
    int t = threadIdx.x;
    int cnt = slotCnt[n];
    if (cnt > SLOTW) cnt = SLOTW;
    if (t == 0) Dcnt = 0;
    if (t < EXPH * HEADS) WexpS[t] = Wexp[t];
    if (t < cnt) pkS[t] = slots[(size_t)n * SLOTW + t];
    // stage own q row as f32
    if (t < 128) {
        unsigned int u = ((const unsigned int*)(Pb + (size_t)n * PW))[t];
        qS[2 * t]     = bflo(u);
        qS[2 * t + 1] = bfhi(u);
    }
    __syncthreads();
    // parallel rank sort by packed (id-major => sorted by edge id; ids unique)
    if (t < cnt) {
        unsigned int pk = pkS[t];
        int rank = 0;
        for (int j = 0; j < cnt; j++) rank += (pkS[j] < pk) ? 1 : 0;
        srtS[rank] = pk;
    }
    if (t < EXPH) {
        float s = 0.f;
        #pragma unroll
        for (int h = 0; h < HEADS; h++) s += MASKV * WexpS[t * HEADS + h];
        MeS[t] = s;
    }
    __syncthreads();
    // dedup (last id wins) + per-edge q.k dots, same phase (both read srtS)
    if (t < cnt) {
        unsigned int d = srtS[t] & 2047u;
        int live = 1;
        for (int j = t + 1; j < cnt; j++)
            if ((srtS[j] & 2047u) == d) { live = 0; break; }
        liveS[t] = live;
        if (live) atomicAdd(&Dcnt, 1);
    }
    {
        int h = t & 7;
        const float* qh = qS + h * 32;
        for (int i = t >> 3; i < cnt; i += 32) {
            int dsti = (int)(srtS[i] & 2047u);
            const uint4* kr = (const uint4*)(Pb + (size_t)dsti * PW + 256 + h * 32);
            float s = 0.f;
            #pragma unroll
            for (int m = 0; m < 4; m++) {
                uint4 u = kr[m];
                const float* qq = qh + m * 8;
                s += qq[0] * bflo(u.x) + qq[1] * bfhi(u.x)
                   + qq[2] * bflo(u.y) + qq[3] * bfhi(u.y)
                   + qq[4] * bflo(u.z) + qq[5] * bfhi(u.z)
                   + qq[6] * bflo(u.w) + qq[7] * bfhi(u.w);
            }
            ewS[i][h] = s;
        }
    }
    __syncthreads();
    // head-expand
    for (int idx = t; idx < cnt * EXPH; idx += 256) {
        int i = idx >> 4, e = idx & 15;
        float a = 0.f;
        #pragma unroll
        for (int hh = 0; hh < HEADS; hh++) a += ewS[i][hh] * WexpS[e * HEADS + hh];
        aS[i][e] = a;
    }
    __syncthreads();
    if (t < EXPH) {
        int e = t;
        float rmax = MeS[e];
        for (int i = 0; i < cnt; i++) if (liveS[i]) rmax = fmaxf(rmax, aS[i][e]);
        rmaxS[e] = rmax;
    }
    __syncthreads();
    for (int idx = t; idx < cnt * EXPH; idx += 256) {
        int i = idx >> 4, e = idx & 15;
        aS[i][e] = liveS[i] ? expf(aS[i][e] - rmaxS[e]) : 0.f;
    }
    __syncthreads();
    int D = Dcnt;
    if (t < EXPH) {
        int e = t;
        float wmE = expf(MeS[e] - rmaxS[e]);
        float denom = (float)(NN - D) * wmE;
        for (int i = 0; i < cnt; i++) denom += aS[i][e];
        denomS[e] = denom;
        wmaskS[e] = wmE / denom;
    }
    __syncthreads();
    // out2[n][c] = vv[n][c] - wmask*colsum[c] + sum_live (wmask - w_i) * vv[dst_i][c]
    int e = t >> 4;
    float wm = wmaskS[e];
    float invD = 1.0f / denomS[e];
    unsigned int uv = ((const unsigned int*)(Pb + (size_t)n * PW + 512))[t];
    float2 cv = ((const float2*)colsum)[t];
    float ax = bflo(uv) - wm * cv.x;
    float ay = bfhi(uv) - wm * cv.y;
    for (int i = 0; i < cnt; i++) {
        if (!liveS[i]) continue;
        float w = wm - aS[i][e] * invD;
        int dsti = (int)(srtS[i] & 2047u);
        unsigned int ub = ((const unsigned int*)(Pb + (size_t)dsti * PW + 512))[t];
        ax += w * bflo(ub);
        ay += w * bfhi(ub);
    }
    unsigned int* o = (unsigned int*)(out2b + (size_t)n * VDIM);
    o[t] = (unsigned int)f2bf(ax) | ((unsigned int)f2bf(ay) << 16);
}

// ---------- final GEMM via MFMA: C (2048x256) = out2b (2048x512) @ Woutb^T ----------
// wave tile 16x16, 4 waves per block side-by-side in cols; grid (128,4) = 512 blocks (8 waves/CU)
__global__ __launch_bounds__(256) void outgemm_mfma_kernel(
    const unsigned short* __restrict__ Ab, const unsigned short* __restrict__ Wb,
    float* __restrict__ C)
{
    int t = threadIdx.x;
    int lane = t & 63;
    int wn = t >> 6;        // 0..3
    int rowT = blockIdx.x * 16;
    int colT = blockIdx.y * 64 + wn * 16;

    int arow = rowT + (lane & 15);
    int koff = (lane >> 4) * 8;

    f32x4 acc = {0.f, 0.f, 0.f, 0.f};

    const unsigned short* ap = Ab + (size_t)arow * VDIM + koff;
    const unsigned short* bp = Wb + (size_t)(colT + (lane & 15)) * VDIM + koff;
    #pragma unroll
    for (int ks = 0; ks < 16; ks++) {
        short8 af = *(const short8*)(ap + ks * 32);
        short8 bf = *(const short8*)(bp + ks * 32);
        acc = __builtin_amdgcn_mfma_f32_16x16x32_bf16(af, bf, acc, 0, 0, 0);
    }
    int crow0 = rowT + (lane >> 4) * 4;
    int ccol  = colT + (lane & 15);
    #pragma unroll
    for (int r = 0; r < 4; r++)
        C[(size_t)(crow0 + r) * DIMM + ccol] = acc[r];
}

extern "C" void kernel_launch(void* const* d_in, const int* in_sizes, int n_in,
                              void* d_out, int out_size, void* d_ws, size_t ws_size,
                              hipStream_t stream) {
    const float* x     = (const float*)d_in[0];
    const float* edges = (const float*)d_in[1];
    const int*   ei32  = (const int*)d_in[2];
    const float* Wq    = (const float*)d_in[3];
    const float* Wk    = (const float*)d_in[4];
    const float* Wv    = (const float*)d_in[5];
    const float* Wev   = (const float*)d_in[6];
    const float* Wexp  = (const float*)d_in[7];
    const float* Wout  = (const float*)d_in[8];
    float* out = (float*)d_out;

    char* ws = (char*)d_ws;
    size_t off = 0;
    auto alloc = [&](size_t bytes) -> void* {
        void* p = ws + off;
        off = (off + bytes + 255) & ~(size_t)255;
        return p;
    };
    unsigned short* Pb    = (unsigned short*)alloc((size_t)NN * PW * 2);   // 4 MB
    float* partial        = (float*)alloc((size_t)CS_BLOCKS * VDIM * 4);   // 256 KB
    float* colsum         = (float*)alloc(VDIM * 4);
    unsigned short* xb    = (unsigned short*)alloc((size_t)NN * DIMM * 2);
    unsigned short* eb    = (unsigned short*)alloc((size_t)NN * DIMM * 2);
    unsigned short* Wqb   = (unsigned short*)alloc((size_t)DIMM * DIMM * 2);
    unsigned short* Wkb   = (unsigned short*)alloc((size_t)DIMM * DIMM * 2);
    unsigned short* Wvb   = (unsigned short*)alloc((size_t)VDIM * DIMM * 2);
    unsigned short* Wevb  = (unsigned short*)alloc((size_t)VDIM * DIMM * 2);
    unsigned short* Woutb = (unsigned short*)alloc((size_t)DIMM * VDIM * 2);
    unsigned short* out2b = (unsigned short*)alloc((size_t)NN * VDIM * 2);
    int* slotCnt          = (int*)alloc(NN * 4);
    unsigned int* slots   = (unsigned int*)alloc((size_t)NN * SLOTW * 4); // 512 KB
    (void)ws_size; (void)in_sizes; (void)n_in; (void)out_size;

    convert_init_kernel<<<1544, 256, 0, stream>>>(x, edges, Wq, Wk, Wv, Wev, Wout,
                                                  xb, eb, Wqb, Wkb, Wvb, Wevb, Woutb,
                                                  slotCnt);
    proj_mfma_kernel<<<dim3(64, 16), 256, 0, stream>>>(xb, eb, Wqb, Wkb, Wvb, Wevb, Pb);
    colsum1_scatter_kernel<<<CS_BLOCKS, 256, 0, stream>>>(Pb, partial, ei32, slotCnt, slots);
    colsum2_kernel<<<1, 512, 0, stream>>>(partial, colsum);
    laplacian_kernel<<<NN, 256, 0, stream>>>(slotCnt, slots, Wexp, colsum, Pb, out2b);
    outgemm_mfma_kernel<<<dim3(128, 4), 256, 0, stream>>>(out2b, Woutb, out);
}